// Round 8
// baseline (155.300 us; speedup 1.0000x reference)
//
#include <hip/hip_runtime.h>
#include <math.h>

// SupervisedContrastiveLoss (R8): barrier-free per-wave GEMM.
//   row_loss_i = log(S_i) - (h_i . csum[lbl_i] - ||h_i||^2) * invT / pos_cnt_i
//   S_i = sum_{lbl_j != lbl_i} exp(s_ij/T)
// R7 post-mortem: gemm was stall-bound (MfmaUtil 13%) -- __syncthreads between
// 64-col steps drained the global_load_lds prefetch queue every ~600 cy of MFMA.
// R8: waves share nothing. Each wave: private 16KB LDS (2x8KB dbuf), 64-row strip
// A resident in 128 VGPRs, 16-col steps, explicit s_waitcnt vmcnt(8) so the
// prefetch stays in flight. Zero __syncthreads in the K-loop. Work: strips of 64
// rows; strip by covers cols [64by,8192) in 16-col steps; t<4 = diagonal 64x64
// (both orders computed -> rowS only); t>=4 -> rowS + colS (verified scheme, R7).

#define NROWS 8192
#define NDIM  256
#define NSTEPS_TOTAL 33024        // sum_by (512 - 4*by), by<128
#define NWAVES 2048               // 512 blocks x 4 waves
#define INVT 14.285714285714286f  // 1/0.07
#define SC_LOG2E (14.285714285714286f * 1.4426950408889634f)  // invT * log2(e)
#define MASK_BIAS -30000.0f       // exp2 bias for same-label pairs -> exp == 0

typedef __attribute__((ext_vector_type(8))) short short8;
typedef __attribute__((ext_vector_type(4))) float f32x4;

__device__ __forceinline__ unsigned short f2bf(float f) {
    unsigned int u = __float_as_uint(f);
    u = u + 0x7fffu + ((u >> 16) & 1u);     // RNE
    return (unsigned short)(u >> 16);
}
__device__ __forceinline__ float bf2f(unsigned short s) {
    return __uint_as_float(((unsigned int)s) << 16);
}

#define GLOAD_LDS16(gp, lp) \
    __builtin_amdgcn_global_load_lds((const __attribute__((address_space(1))) void*)(gp), \
                                     (__attribute__((address_space(3))) void*)(lp), 16, 0, 0)
// wait until <= n VMEM ops outstanding (gfx9 encoding: vmcnt[3:0], exp=7, lgkm=0xF)
#define WAITVM(n) __builtin_amdgcn_s_waitcnt(0x0F70 | (n))

// ================= prep: normalize -> hA bf16; selfsim; neg=0; csum/cnt partials
__global__ __launch_bounds__(256) void prep_kernel(const float* __restrict__ x,
                                                   const int* __restrict__ labels,
                                                   unsigned short* __restrict__ hA,
                                                   float* __restrict__ selfsim,
                                                   float* __restrict__ neg,
                                                   float* __restrict__ csum_part,
                                                   float* __restrict__ cnt_part,
                                                   int* __restrict__ ticket) {
    __shared__ float sdata[4][2][256];
    __shared__ float cw[4];
    const int tid = threadIdx.x, blk = blockIdx.x;
    const int w = tid >> 6, lane = tid & 63;
    const int row0 = blk * 32;

    float a0[4] = {0.f, 0.f, 0.f, 0.f}, a1[4] = {0.f, 0.f, 0.f, 0.f};
    int c1 = 0;
    for (int i = 0; i < 8; ++i) {
        int row = row0 + w * 8 + i;
        float4 v = *(const float4*)(x + (size_t)row * NDIM + lane * 4);
        float ss = v.x * v.x + v.y * v.y + v.z * v.z + v.w * v.w;
#pragma unroll
        for (int o = 32; o >= 1; o >>= 1) ss += __shfl_xor(ss, o, 64);
        float inv = 1.0f / fmaxf(sqrtf(ss), 1e-12f);
        ushort4 b;
        b.x = f2bf(v.x * inv); b.y = f2bf(v.y * inv);
        b.z = f2bf(v.z * inv); b.w = f2bf(v.w * inv);
        float f0 = bf2f(b.x), f1 = bf2f(b.y), f2 = bf2f(b.z), f3 = bf2f(b.w);
        float s2 = f0 * f0 + f1 * f1 + f2 * f2 + f3 * f3;
#pragma unroll
        for (int o = 32; o >= 1; o >>= 1) s2 += __shfl_xor(s2, o, 64);
        *(ushort4*)(hA + (size_t)row * NDIM + lane * 4) = b;
        if (lane == 0) { selfsim[row] = s2; neg[row] = 0.f; }
        int l = labels[row] & 1;
        c1 += l;
        if (l) { a1[0] += f0; a1[1] += f1; a1[2] += f2; a1[3] += f3; }
        else   { a0[0] += f0; a0[1] += f1; a0[2] += f2; a0[3] += f3; }
    }
#pragma unroll
    for (int k = 0; k < 4; ++k) {
        sdata[w][0][lane * 4 + k] = a0[k];
        sdata[w][1][lane * 4 + k] = a1[k];
    }
    if (lane == 0) cw[w] = (float)c1;
    __syncthreads();
    float s0 = sdata[0][0][tid] + sdata[1][0][tid] + sdata[2][0][tid] + sdata[3][0][tid];
    float s1 = sdata[0][1][tid] + sdata[1][1][tid] + sdata[2][1][tid] + sdata[3][1][tid];
    csum_part[blk * 512 + tid] = s0;
    csum_part[blk * 512 + 256 + tid] = s1;
    if (tid == 0) {
        float c = cw[0] + cw[1] + cw[2] + cw[3];
        cnt_part[blk * 2 + 1] = c;
        cnt_part[blk * 2 + 0] = 32.0f - c;
        if (blk == 0) ticket[0] = 0;
    }
}

// ================= csum finalize: one block, writes csum[512] and cnt[2]
__global__ __launch_bounds__(256) void csumfin_kernel(const float* __restrict__ csum_part,
                                                      const float* __restrict__ cnt_part,
                                                      float* __restrict__ csum,
                                                      float* __restrict__ cnt) {
    const int tid = threadIdx.x;
    float s0 = 0.f, s1 = 0.f;
    for (int b = 0; b < 256; ++b) {
        s0 += csum_part[b * 512 + tid];
        s1 += csum_part[b * 512 + 256 + tid];
    }
    csum[tid] = s0;
    csum[256 + tid] = s1;
    if (tid < 2) {
        float c = 0.f;
        for (int b = 0; b < 256; ++b) c += cnt_part[b * 2 + tid];
        cnt[tid] = c;
    }
}

// stage one 16-col x K=256 B-tile (8 KB) into the wave's private LDS buffer.
// LDS: col-major 512 B/col; slot s of col holds global k-chunk s ^ (col&7).
__device__ __forceinline__ void stage16(const unsigned short* __restrict__ hA,
                                        unsigned char* dst, int col0g, int lane) {
#pragma unroll
    for (int t = 0; t < 8; ++t) {
        int colLocal = t * 2 + (lane >> 5);
        int g = (lane & 31) ^ (colLocal & 7);
        const unsigned short* gp = hA + (size_t)(col0g + colLocal) * NDIM + g * 8;
        GLOAD_LDS16(gp, dst + t * 1024);
    }
}

// ================= barrier-free triangle GEMM over balanced wave-step list
__global__ __launch_bounds__(256, 2) void gemm_kernel(const unsigned short* __restrict__ hA,
                                                      const int* __restrict__ labels,
                                                      float* __restrict__ neg) {
    __shared__ __align__(16) unsigned char smem[65536];   // 4 waves x 2 x 8 KB
    const int tid = threadIdx.x, blk = blockIdx.x;
    const int w = tid >> 6, lane = tid & 63;
    const int quad = lane >> 4, l15 = lane & 15;
    unsigned char* wbuf = smem + w * 16384;

    const int wgid = blk * 4 + w;
    const int s0 = (int)((long long)wgid * NSTEPS_TOTAL / NWAVES);
    const int s1 = (int)((long long)(wgid + 1) * NSTEPS_TOTAL / NWAVES);

    // locate starting strip: steps before strip by = by*(514-2*by)
    int by = 0;
    while (by < 127 && (by + 1) * (514 - 2 * (by + 1)) <= s0) ++by;
    int t = s0 - by * (514 - 2 * by);

    // A-fragments: this wave's 64-row strip x K=256 (128 VGPR), + row-label mask
    short8 a[4][8];
    unsigned rl;
    {
        int row0 = by * 64;
#pragma unroll
        for (int mt = 0; mt < 4; ++mt)
#pragma unroll
            for (int ki = 0; ki < 8; ++ki)
                a[mt][ki] = *(const short8*)(hA +
                    (size_t)(row0 + mt * 16 + l15) * NDIM + ki * 32 + quad * 8);
        rl = 0;
#pragma unroll
        for (int mt = 0; mt < 4; ++mt)
#pragma unroll
            for (int r = 0; r < 4; ++r)
                rl |= (unsigned)(labels[row0 + mt * 16 + quad * 4 + r] & 1) << (mt * 4 + r);
    }

    float rowS[4][4];
#pragma unroll
    for (int mt = 0; mt < 4; ++mt)
#pragma unroll
        for (int r = 0; r < 4; ++r) rowS[mt][r] = 0.f;

    stage16(hA, wbuf, by * 64 + t * 16, lane);

    for (int s = s0; s < s1; ++s) {
        const int buf = (s - s0) & 1;
        const int nst = 512 - 4 * by;
        const bool strip_end = (t == nst - 1);
        const int byn = strip_end ? by + 1 : by;
        const int tn  = strip_end ? 0 : t + 1;
        const bool pf = (s + 1 < s1);
        if (pf) {
            stage16(hA, wbuf + (buf ^ 1) * 8192, byn * 64 + tn * 16, lane);
            WAITVM(8);     // drain step-s loads; step-(s+1) prefetch stays in flight
        } else {
            WAITVM(0);
        }

        const int col0 = by * 64 + t * 16;
        const int cl = labels[col0 + l15] & 1;
        const unsigned diff = rl ^ (cl ? 0xFFFFu : 0u);   // bit=1 -> labels differ

        const unsigned short* Bb = (const unsigned short*)(wbuf + buf * 8192);
        f32x4 acc[4];
#pragma unroll
        for (int mt = 0; mt < 4; ++mt) acc[mt] = (f32x4){0.f, 0.f, 0.f, 0.f};
#pragma unroll
        for (int ki = 0; ki < 8; ++ki) {
            int sw = (ki * 4 + quad) ^ (l15 & 7);
            short8 b = *(const short8*)(Bb + l15 * 256 + sw * 8);
#pragma unroll
            for (int mt = 0; mt < 4; ++mt)
                acc[mt] = __builtin_amdgcn_mfma_f32_16x16x32_bf16(a[mt][ki], b, acc[mt], 0, 0, 0);
        }
        float colS = 0.f;
#pragma unroll
        for (int mt = 0; mt < 4; ++mt)
#pragma unroll
            for (int r = 0; r < 4; ++r) {
                float bias = ((diff >> (mt * 4 + r)) & 1u) ? 0.f : MASK_BIAS;
                float e = exp2f(fmaf(acc[mt][r], SC_LOG2E, bias));
                rowS[mt][r] += e;
                colS += e;
            }
        if (t >= 4) {   // off-diagonal step: credit the pair's other side
            colS += __shfl_xor(colS, 16, 64);
            colS += __shfl_xor(colS, 32, 64);
            if (quad == 0) atomicAdd(&neg[col0 + l15], colS);
        }
        if (strip_end || s == s1 - 1) {
#pragma unroll
            for (int o = 1; o < 16; o <<= 1)
#pragma unroll
                for (int mt = 0; mt < 4; ++mt)
#pragma unroll
                    for (int r = 0; r < 4; ++r)
                        rowS[mt][r] += __shfl_xor(rowS[mt][r], o, 64);
            if (l15 == 0) {
                int row0 = by * 64;
#pragma unroll
                for (int mt = 0; mt < 4; ++mt)
#pragma unroll
                    for (int r = 0; r < 4; ++r)
                        atomicAdd(&neg[row0 + mt * 16 + quad * 4 + r], rowS[mt][r]);
            }
            if (pf && strip_end) {   // next strip: reload A, reset
                int row0n = byn * 64;
#pragma unroll
                for (int mt = 0; mt < 4; ++mt)
#pragma unroll
                    for (int ki = 0; ki < 8; ++ki)
                        a[mt][ki] = *(const short8*)(hA +
                            (size_t)(row0n + mt * 16 + l15) * NDIM + ki * 32 + quad * 8);
                rl = 0;
#pragma unroll
                for (int mt = 0; mt < 4; ++mt)
#pragma unroll
                    for (int r = 0; r < 4; ++r)
                        rl |= (unsigned)(labels[row0n + mt * 16 + quad * 4 + r] & 1) << (mt * 4 + r);
#pragma unroll
                for (int mt = 0; mt < 4; ++mt)
#pragma unroll
                    for (int r = 0; r < 4; ++r) rowS[mt][r] = 0.f;
            }
        }
        by = byn; t = tn;
    }
}

// ================= rowloss + ticketed finalize (last block writes out)
__global__ __launch_bounds__(256) void rowloss_kernel(const unsigned short* __restrict__ hA,
                                                      const int* __restrict__ labels,
                                                      const float* __restrict__ neg,
                                                      const float* __restrict__ selfsim,
                                                      const float* __restrict__ csum,
                                                      const float* __restrict__ cnt,
                                                      float* __restrict__ pbuf,
                                                      int* __restrict__ ticket,
                                                      float* __restrict__ out) {
    __shared__ float csumS[2][256];
    __shared__ float red[8];
    __shared__ int lastFlag;
    const int tid = threadIdx.x, blk = blockIdx.x;
    const int w = tid >> 6, lane = tid & 63;

    csumS[0][tid] = csum[tid];
    csumS[1][tid] = csum[256 + tid];
    __syncthreads();
    const float c0v = cnt[0], c1v = cnt[1];

    const int row0 = blk * 128;
    float wsum = 0.f, wcnt = 0.f;
    for (int i = 0; i < 32; ++i) {
        int row = row0 + w * 32 + i;
        int l = labels[row] & 1;
        ushort4 hv = *(const ushort4*)(hA + (size_t)row * NDIM + lane * 4);
        const float* cv = &csumS[l][lane * 4];
        float dot = bf2f(hv.x) * cv[0] + bf2f(hv.y) * cv[1] +
                    bf2f(hv.z) * cv[2] + bf2f(hv.w) * cv[3];
#pragma unroll
        for (int o = 32; o >= 1; o >>= 1) dot += __shfl_xor(dot, o, 64);
        if (lane == 0) {
            float pc = (l ? c1v : c0v) - 1.0f;
            float S = neg[row];
            if (pc > 0.5f) {
                wcnt += 1.f;
                if (S > 0.f)
                    wsum += logf(S) - (dot - selfsim[row]) * INVT / pc;
            }
        }
    }
    if (lane == 0) { red[w] = wsum; red[4 + w] = wcnt; }
    __syncthreads();
    if (tid == 0) {
        atomicExch(&pbuf[blk],      red[0] + red[1] + red[2] + red[3]);
        atomicExch(&pbuf[64 + blk], red[4] + red[5] + red[6] + red[7]);
        __threadfence();
        int old = atomicAdd(ticket, 1);
        lastFlag = (old == 63) ? 1 : 0;
    }
    __syncthreads();
    if (lastFlag && tid < 64) {
        __threadfence();
        float v = atomicAdd(&pbuf[tid], 0.0f);        // device-scope atomic read
        float c = atomicAdd(&pbuf[64 + tid], 0.0f);
#pragma unroll
        for (int o = 32; o >= 1; o >>= 1) {
            v += __shfl_xor(v, o, 64);
            c += __shfl_xor(c, o, 64);
        }
        if (tid == 0) out[0] = (c > 0.f) ? v / c : 0.f;
    }
}

extern "C" void kernel_launch(void* const* d_in, const int* in_sizes, int n_in,
                              void* d_out, int out_size, void* d_ws, size_t ws_size,
                              hipStream_t stream) {
    const float* x = (const float*)d_in[0];
    const int* labels = (const int*)d_in[1];

    unsigned short* hA = (unsigned short*)d_ws;              // N*D bf16 = 4 MB
    float* wsf       = (float*)d_ws;
    float* selfsim   = wsf + (size_t)NROWS * NDIM / 2;       // 8192
    float* neg       = selfsim + NROWS;                      // 8192
    float* csum_part = neg + NROWS;                          // 256*512
    float* cnt_part  = csum_part + 256 * 512;                // 512
    float* csum      = cnt_part + 512;                       // 512
    float* cnt       = csum + 512;                           // 2
    float* pbuf      = cnt + 2;                              // 128
    int*   ticket    = (int*)(pbuf + 128);                   // 1

    prep_kernel<<<256, 256, 0, stream>>>(x, labels, hA, selfsim, neg, csum_part, cnt_part, ticket);
    csumfin_kernel<<<1, 256, 0, stream>>>(csum_part, cnt_part, csum, cnt);
    gemm_kernel<<<512, 256, 0, stream>>>(hA, labels, neg);
    rowloss_kernel<<<64, 256, 0, stream>>>(hA, labels, neg, selfsim, csum, cnt,
                                           pbuf, ticket, (float*)d_out);
}